// Round 11
// baseline (78.007 us; speedup 1.0000x reference)
//
#include <hip/hip_runtime.h>
#include <math.h>

#define BATCH 32
#define CH    128
#define HW    4096   // 64*64

typedef short short8 __attribute__((ext_vector_type(8)));   // 8 bf16 (4 VGPRs)
typedef float f32x4  __attribute__((ext_vector_type(4)));   // MFMA accumulator

#define SWZ(n) ((((n) >> 2) & 7) << 3)   // XOR swizzle of k-index by row

__device__ __forceinline__ unsigned short f2bf(float f) {   // RNE float->bf16
    unsigned int u = __float_as_uint(f);
    u = (u + 0x7FFF + ((u >> 16) & 1)) >> 16;
    return (unsigned short)u;
}
__device__ __forceinline__ float bf2f(unsigned short s) {
    return __uint_as_float(((unsigned int)s) << 16);
}
__device__ __forceinline__ float comp(const float4& v, int r) {  // static r after unroll
    return (r == 0) ? v.x : (r == 1) ? v.y : (r == 2) ? v.z : v.w;
}

// ---------------------------------------------------------------------------
// Kernel 1: pooled[b*C+c] = mean over HW of condition[b,c,:,:]
// ---------------------------------------------------------------------------
__global__ __launch_bounds__(256) void pool_kernel(const float* __restrict__ cond,
                                                   float* __restrict__ pooled) {
    int bc = blockIdx.x;
    const float4* base = (const float4*)(cond + (size_t)bc * HW);
    int tid = threadIdx.x;
    float s = 0.f;
#pragma unroll
    for (int k = 0; k < 4; ++k) {
        float4 v = base[tid + k * 256];
        s += v.x + v.y + v.z + v.w;
    }
    for (int off = 32; off; off >>= 1) s += __shfl_down(s, off, 64);
    __shared__ float red[4];
    if ((tid & 63) == 0) red[tid >> 6] = s;
    __syncthreads();
    if (tid == 0) pooled[bc] = (red[0] + red[1] + red[2] + red[3]) * (1.0f / HW);
}

// ---------------------------------------------------------------------------
// Kernel 2: wmat[b][o][i] = dot(pooled[b], w_lin[o*C+i]) + b_lin + (o==i)
// fp32 copy for logdet diagonal + bf16 copy for both MFMA consumers.
// Block 0 also zeroes the logdet completion counter for this launch.
// ---------------------------------------------------------------------------
__global__ __launch_bounds__(256) void wmat_kernel(const float* __restrict__ pooled,
                                                   const float* __restrict__ w_lin,
                                                   const float* __restrict__ b_lin,
                                                   float* __restrict__ wmat,
                                                   unsigned short* __restrict__ wmatb,
                                                   unsigned* __restrict__ counter) {
    if (blockIdx.x == 0 && threadIdx.x == 0) *counter = 0u;

    __shared__ float4 pl[BATCH * CH / 4];   // pooled staged: pl[b*32 + k4]
    int tid = threadIdx.x;
    const float4* p4 = (const float4*)pooled;
    for (int idx = tid; idx < BATCH * CH / 4; idx += 256) pl[idx] = p4[idx];
    __syncthreads();

    int n = blockIdx.x * 256 + tid;
    const float4* row = (const float4*)(w_lin + (size_t)n * CH);
    float bl = b_lin[n];
    float acc[BATCH];
#pragma unroll
    for (int b = 0; b < BATCH; ++b) acc[b] = bl;

    for (int k4 = 0; k4 < CH / 4; ++k4) {
        float4 wv = row[k4];
#pragma unroll
        for (int b = 0; b < BATCH; ++b) {
            float4 pv = pl[b * 32 + k4];
            acc[b] += pv.x * wv.x + pv.y * wv.y + pv.z * wv.z + pv.w * wv.w;
        }
    }
    int o = n >> 7, i = n & 127;
    float diag = (o == i) ? 1.0f : 0.0f;
#pragma unroll
    for (int b = 0; b < BATCH; ++b) {
        float v = acc[b] + diag;
        wmat [(size_t)b * (CH * CH) + n] = v;
        wmatb[(size_t)b * (CH * CH) + n] = f2bf(v);
    }
}

// ---------------------------------------------------------------------------
// Kernel 3 (fused):
//   blocks 0..31: per-sample log|det W| via MFMA series (validated r4-r10).
//     Last finishing block sums the 32 partials IN ORDER (deterministic).
//   blocks 32..4127: MFMA conv, 32-PIXEL tiles (grid = 4096 = ~4 residency
//     generations at 4 blocks/CU): block starts stagger continuously so
//     read bursts of new blocks overlap compute/write of older ones --
//     breaks the single-generation read/compute/write lockstep.
//     Plain float4 stores (NT stores write-amplified 65->86 MB, r9).
//     XCD-bijective swizzle keeps each XCD's W + inp reads L2-local.
// ---------------------------------------------------------------------------
__global__ __launch_bounds__(256, 4) void fused_kernel(const float* __restrict__ inp,
                                                       const float* __restrict__ wmat,
                                                       const unsigned short* __restrict__ wmatb,
                                                       float* __restrict__ out,
                                                       float* __restrict__ partial,
                                                       unsigned* __restrict__ counter,
                                                       float* __restrict__ out_scalar) {
    __shared__ __align__(16) short X[CH * 136];   // logdet: full 34816 B; conv: first 8704 B
    int tid  = threadIdx.x;
    int lane = tid & 63;
    int ln   = lane & 15;                // row/col within 16
    int lg   = lane >> 4;                // k-group 0..3
    int och0 = (tid >> 6) * 32;          // wave's m-base

    if (blockIdx.x < BATCH) {
        // ---------------- logdet (MFMA series, unchanged) ----------------
        int b = blockIdx.x;
        const float*          Wb = wmat  + (size_t)b * CH * CH;
        const unsigned short* wb = wmatb + (size_t)b * CH * CH;

        // ---- stage ÊT[n][k^swz] = Ê[k][n], diag zeroed (transpose of W rows)
        {
            int q  = tid & 31;           // col-quad: n = 4q..4q+3
            int ks = tid >> 5;           // 0..7
            const float* sb = Wb + 4 * q;
#pragma unroll
            for (int m = 0; m < 4; ++m) {
                int k0 = m * 32 + ks * 4;
                float4 r0 = *(const float4*)(sb + (size_t)(k0 + 0) * CH);
                float4 r1 = *(const float4*)(sb + (size_t)(k0 + 1) * CH);
                float4 r2 = *(const float4*)(sb + (size_t)(k0 + 2) * CH);
                float4 r3 = *(const float4*)(sb + (size_t)(k0 + 3) * CH);
#pragma unroll
                for (int r = 0; r < 4; ++r) {
                    int n = 4 * q + r;
                    float a0 = comp(r0, r), a1 = comp(r1, r);
                    float a2 = comp(r2, r), a3 = comp(r3, r);
                    if (k0 + 0 == n) a0 = 0.f;
                    if (k0 + 1 == n) a1 = 0.f;
                    if (k0 + 2 == n) a2 = 0.f;
                    if (k0 + 3 == n) a3 = 0.f;
                    ushort4 v;
                    v.x = f2bf(a0); v.y = f2bf(a1); v.z = f2bf(a2); v.w = f2bf(a3);
                    *(ushort4*)&X[n * 136 + (k0 ^ SWZ(n))] = v;
                }
            }
        }

        // ---- A fragments: Ê rows from wmatb, diag slot zeroed
        short8 afr[2][4];
#pragma unroll
        for (int mt = 0; mt < 2; ++mt) {
            int row = och0 + mt * 16 + ln;
#pragma unroll
            for (int g = 0; g < 4; ++g) {
                short8 v = *(const short8*)&wb[(size_t)row * CH + g * 32 + lg * 8];
#pragma unroll
                for (int j = 0; j < 8; ++j)
                    if (g * 32 + lg * 8 + j == row) v[j] = 0;
                afr[mt][g] = v;
            }
        }
        __syncthreads();

        // ---- D = Ê² via MFMA
        f32x4 acc[2][8];
#pragma unroll
        for (int mt = 0; mt < 2; ++mt)
#pragma unroll
            for (int nt = 0; nt < 8; ++nt) acc[mt][nt] = (f32x4){0.f, 0.f, 0.f, 0.f};
#pragma unroll
        for (int g = 0; g < 4; ++g) {
#pragma unroll
            for (int nt = 0; nt < 8; ++nt) {
                int n = nt * 16 + ln;
                short8 bfr = *(const short8*)&X[n * 136 + ((g * 32 + lg * 8) ^ SWZ(n))];
                acc[0][nt] = __builtin_amdgcn_mfma_f32_16x16x32_bf16(afr[0][g], bfr, acc[0][nt], 0, 0, 0);
                acc[1][nt] = __builtin_amdgcn_mfma_f32_16x16x32_bf16(afr[1][g], bfr, acc[1][nt], 0, 0, 0);
            }
        }

        // ---- traces: t3 (ÊT still in LDS) + diagonal terms
        float ld = 0.f;
#pragma unroll
        for (int mt = 0; mt < 2; ++mt) {
#pragma unroll
            for (int nt = 0; nt < 8; ++nt) {
#pragma unroll
                for (int reg = 0; reg < 4; ++reg) {
                    int row = och0 + mt * 16 + lg * 4 + reg;
                    int col = nt * 16 + ln;
                    float v = acc[mt][nt][reg];
                    float eT = bf2f((unsigned short)X[row * 136 + (col ^ SWZ(row))]);
                    ld += v * eT * (1.f / 3.f);
                    if (row == col) {
                        float d = Wb[(size_t)row * CH + row] - 1.0f;
                        ld += logf(fabsf(1.f + d)) + v * d - 0.5f * v;
                    }
                }
            }
        }
        __syncthreads();   // all ÊT reads done -> reuse LDS for D

        // ---- write D (bf16) for the transpose needed by tr(Ê⁴)
#pragma unroll
        for (int mt = 0; mt < 2; ++mt)
#pragma unroll
            for (int nt = 0; nt < 8; ++nt)
#pragma unroll
                for (int reg = 0; reg < 4; ++reg) {
                    int row = och0 + mt * 16 + lg * 4 + reg;
                    int col = nt * 16 + ln;
                    X[row * 136 + (col ^ SWZ(row))] = (short)f2bf(acc[mt][nt][reg]);
                }
        __syncthreads();

        // ---- t4 = sum D[r][c]*D[c][r]
#pragma unroll
        for (int mt = 0; mt < 2; ++mt)
#pragma unroll
            for (int nt = 0; nt < 8; ++nt)
#pragma unroll
                for (int reg = 0; reg < 4; ++reg) {
                    int row = och0 + mt * 16 + lg * 4 + reg;
                    int col = nt * 16 + ln;
                    float dT = bf2f((unsigned short)X[col * 136 + (row ^ SWZ(col))]);
                    ld -= acc[mt][nt][reg] * dT * 0.25f;
                }

        for (int off = 32; off; off >>= 1) ld += __shfl_down(ld, off, 64);
        __syncthreads();
        float* red = (float*)X;
        if (lane == 0) red[tid >> 6] = ld;
        __syncthreads();

        // ---- publish partial; last block (deterministic order) writes scalar
        if (tid == 0) {
            float my = red[0] + red[1] + red[2] + red[3];
            __hip_atomic_store(&partial[b], my, __ATOMIC_RELAXED,
                               __HIP_MEMORY_SCOPE_AGENT);
            __threadfence();
            unsigned prev = __hip_atomic_fetch_add(counter, 1u, __ATOMIC_ACQ_REL,
                                                   __HIP_MEMORY_SCOPE_AGENT);
            if (prev == BATCH - 1) {
                __threadfence();
                float s = 0.f;
#pragma unroll
                for (int i = 0; i < BATCH; ++i)
                    s += __hip_atomic_load(&partial[i], __ATOMIC_RELAXED,
                                           __HIP_MEMORY_SCOPE_AGENT);
                out_scalar[0] = s * 128.0f;
            }
        }
    } else {
        // ---------------- MFMA conv, 32-pixel tiles ----------------
        int cb = blockIdx.x - BATCH;         // 0..4095
        cb = (cb & 7) * 512 + (cb >> 3);     // bijective XCD swizzle (4096 = 8*512)
        int b    = cb >> 7;                  // 0..31
        int tile = cb & 127;                 // 0..127
        int pix0 = tile * 32;

        int q  = tid & 7;                    // pixel-quad: pix = 4q..4q+3 (0..31)
        int ks = tid >> 3;                   // 0..31 (k rows ks*4..ks*4+3)
        const float* sb = inp + (size_t)b * CH * HW + pix0 + 4 * q;

        // ---- 4 X loads per thread (16 KB/block)
        float4 stg[4];
#pragma unroll
        for (int r = 0; r < 4; ++r)
            stg[r] = *(const float4*)(sb + (size_t)(ks * 4 + r) * HW);

        // ---- A fragments (W bf16 rows, XCD-L2-hot) while X loads in flight
        const unsigned short* wb = wmatb + (size_t)b * CH * CH;
        short8 afr[2][4];
#pragma unroll
        for (int mt = 0; mt < 2; ++mt)
#pragma unroll
            for (int g = 0; g < 4; ++g)
                afr[mt][g] = *(const short8*)&wb[(size_t)(och0 + mt * 16 + ln) * CH + g * 32 + lg * 8];

        // ---- convert -> bf16 LDS [pix][k^swz] (in-thread 4x4 transpose)
        {
            int k0 = ks * 4;
#pragma unroll
            for (int r = 0; r < 4; ++r) {
                int pix = 4 * q + r;
                ushort4 v;
                v.x = f2bf(comp(stg[0], r));
                v.y = f2bf(comp(stg[1], r));
                v.z = f2bf(comp(stg[2], r));
                v.w = f2bf(comp(stg[3], r));
                *(ushort4*)&X[pix * 136 + (k0 ^ SWZ(pix))] = v;
            }
        }
        __syncthreads();

        // ---- MFMA: acc[mt][nt] = D[pix-tile nt][och-tile mt]
        f32x4 acc[2][2];
#pragma unroll
        for (int mt = 0; mt < 2; ++mt)
#pragma unroll
            for (int nt = 0; nt < 2; ++nt) acc[mt][nt] = (f32x4){0.f, 0.f, 0.f, 0.f};

#pragma unroll
        for (int g = 0; g < 4; ++g) {
#pragma unroll
            for (int nt = 0; nt < 2; ++nt) {
                int pix = nt * 16 + ln;
                short8 bfr = *(const short8*)&X[pix * 136 + ((g * 32 + lg * 8) ^ SWZ(pix))];
                acc[0][nt] = __builtin_amdgcn_mfma_f32_16x16x32_bf16(bfr, afr[0][g], acc[0][nt], 0, 0, 0);
                acc[1][nt] = __builtin_amdgcn_mfma_f32_16x16x32_bf16(bfr, afr[1][g], acc[1][nt], 0, 0, 0);
            }
        }

        // ---- plain float4 stores: D col=ln(och), row=lg*4+reg(pix)
        float* ob = out + (size_t)b * CH * HW + pix0;
#pragma unroll
        for (int mt = 0; mt < 2; ++mt) {
            int och = och0 + mt * 16 + ln;
#pragma unroll
            for (int nt = 0; nt < 2; ++nt) {
                int px = nt * 16 + lg * 4;
                float4 v = make_float4(acc[mt][nt][0], acc[mt][nt][1],
                                       acc[mt][nt][2], acc[mt][nt][3]);
                *(float4*)(ob + (size_t)och * HW + px) = v;
            }
        }
    }
}

// ---------------------------------------------------------------------------
extern "C" void kernel_launch(void* const* d_in, const int* in_sizes, int n_in,
                              void* d_out, int out_size, void* d_ws, size_t ws_size,
                              hipStream_t stream) {
    const float* inp   = (const float*)d_in[0];
    const float* cond  = (const float*)d_in[1];
    const float* w_lin = (const float*)d_in[2];
    const float* b_lin = (const float*)d_in[3];
    float* out = (float*)d_out;

    float* pooled          = (float*)d_ws;                    // 4096 floats
    float* wmat            = pooled + BATCH * CH;             // 524288 floats
    float* partial         = wmat + BATCH * CH * CH;          // 32 floats
    unsigned* counter      = (unsigned*)(partial + 32);       // 1 uint
    unsigned short* wmatb  = (unsigned short*)(partial + 64); // 524288 bf16

    pool_kernel<<<BATCH * CH, 256, 0, stream>>>(cond, pooled);
    wmat_kernel<<<CH * CH / 256, 256, 0, stream>>>(pooled, w_lin, b_lin, wmat, wmatb, counter);
    fused_kernel<<<BATCH + BATCH * 128, 256, 0, stream>>>(inp, wmat, wmatb, out, partial,
                                                          counter, out + (size_t)BATCH * CH * HW);
}